// Round 8
// baseline (41.151 us; speedup 1.0000x reference)
//
#include <hip/hip_runtime.h>
#include <cmath>

#define MARGIN 0.1f
#define EPS 1e-5f

#define TPB    256
#define BLOCKS 1024
#define RPT    4   // rows per 4-lane group (grid-strided)

typedef float vf4 __attribute__((ext_vector_type(4)));

// Single fused kernel: depth-2 software-pipelined loads (R5 structure, best
// timed config), block partial reduced in-wave, then one device-scope
// atomicAdd of partial*inv_n into d_out[0] (zeroed by a 4B memset each call).
// FP-atomic ordering noise ~1e-6 << 2.7e-3 validation threshold.
__global__ __launch_bounds__(TPB, 4) void hinge_fused_kernel(
    const float* __restrict__ outp,   // [N,64] "output" (v)
    const float* __restrict__ tgt,    // [N,64] "target" (u)
    const int*   __restrict__ nidx,   // [N] negative indices
    float* __restrict__ out,          // [1] result accumulator (pre-zeroed)
    float inv_n,
    int n)
{
    const int g   = blockIdx.x * TPB + threadIdx.x;
    const int grp = g >> 2;
    const int sub = g & 3;
    const int G   = (BLOCKS * TPB) >> 2;   // groups in grid

    int  rows[RPT];
    bool valid[RPT];
    #pragma unroll
    for (int p = 0; p < RPT; ++p) {
        const int r = grp + p * G;
        valid[p] = (r < n);
        rows[p]  = valid[p] ? r : 0;
    }

    // preload ALL negative indices up front — no idx->gather chain in the loop
    long j[RPT];
    #pragma unroll
    for (int p = 0; p < RPT; ++p) j[p] = (long)nidx[rows[p]];

    const vf4* ob = reinterpret_cast<const vf4*>(outp);
    const vf4* tb = reinterpret_cast<const vf4*>(tgt);

    float loss = 0.0f;

    vf4 oA[4], tA[4], nA[4];   // buffer A (rows 0, 2)
    vf4 oB[4], tB[4], nB[4];   // buffer B (rows 1, 3)

#define LOADROW(BO, BT, BN, P) do {                                   \
        const vf4* o_ = ob + (size_t)rows[P] * 16 + sub;              \
        const vf4* t_ = tb + (size_t)rows[P] * 16 + sub;              \
        const vf4* n_ = tb + (size_t)j[P]    * 16 + sub;              \
        _Pragma("unroll")                                             \
        for (int k = 0; k < 4; ++k) {                                 \
            BO[k] = o_[k * 4];                                        \
            BT[k] = t_[k * 4];                                        \
            BN[k] = n_[k * 4];                                        \
        }                                                             \
    } while (0)

#define COMPUTE(BO, BT, BN, P) do {                                   \
        float sp = 0.f, sn = 0.f, un = 0.f, vn = 0.f, wn = 0.f;       \
        _Pragma("unroll")                                             \
        for (int k = 0; k < 4; ++k) {                                 \
            const vf4 ov = BO[k], tv = BT[k], nv = BN[k];             \
            float d;                                                  \
            d = tv.x - ov.x; sp += d * d;                             \
            d = tv.y - ov.y; sp += d * d;                             \
            d = tv.z - ov.z; sp += d * d;                             \
            d = tv.w - ov.w; sp += d * d;                             \
            d = nv.x - ov.x; sn += d * d;                             \
            d = nv.y - ov.y; sn += d * d;                             \
            d = nv.z - ov.z; sn += d * d;                             \
            d = nv.w - ov.w; sn += d * d;                             \
            un += tv.x * tv.x + tv.y * tv.y + tv.z * tv.z + tv.w * tv.w; \
            vn += ov.x * ov.x + ov.y * ov.y + ov.z * ov.z + ov.w * ov.w; \
            wn += nv.x * nv.x + nv.y * nv.y + nv.z * nv.z + nv.w * nv.w; \
        }                                                             \
        _Pragma("unroll")                                             \
        for (int mask = 1; mask <= 2; mask <<= 1) {                   \
            sp += __shfl_xor(sp, mask, 64);                           \
            sn += __shfl_xor(sn, mask, 64);                           \
            un += __shfl_xor(un, mask, 64);                           \
            vn += __shfl_xor(vn, mask, 64);                           \
            wn += __shfl_xor(wn, mask, 64);                           \
        }                                                             \
        if (sub == 0 && valid[P]) {                                   \
            const float xp = 1.0f + 2.0f * sp / ((1.0f - un) * (1.0f - vn)); \
            const float xn = 1.0f + 2.0f * sn / ((1.0f - wn) * (1.0f - vn)); \
            loss += fmaxf(MARGIN + acoshf(fmaxf(xp, 1.0f + EPS))      \
                                 - acoshf(fmaxf(xn, 1.0f + EPS)), 0.0f); \
        }                                                             \
    } while (0)

    LOADROW(oA, tA, nA, 0);
    LOADROW(oB, tB, nB, 1);
    COMPUTE(oA, tA, nA, 0);
    LOADROW(oA, tA, nA, 2);
    COMPUTE(oB, tB, nB, 1);
    LOADROW(oB, tB, nB, 3);
    COMPUTE(oA, tA, nA, 2);
    COMPUTE(oB, tB, nB, 3);

#undef LOADROW
#undef COMPUTE

    // wave(64) shuffle reduce
    #pragma unroll
    for (int off = 32; off > 0; off >>= 1)
        loss += __shfl_down(loss, off, 64);

    __shared__ float ws[4];
    const int lane = threadIdx.x & 63;
    const int wid  = threadIdx.x >> 6;
    if (lane == 0) ws[wid] = loss;
    __syncthreads();
    if (threadIdx.x == 0)
        atomicAdd(out, (ws[0] + ws[1] + ws[2] + ws[3]) * inv_n);
}

extern "C" void kernel_launch(void* const* d_in, const int* in_sizes, int n_in,
                              void* d_out, int out_size, void* d_ws, size_t ws_size,
                              hipStream_t stream) {
    const float* outp = (const float*)d_in[0];  // "output" [N,64]
    const float* tgt  = (const float*)d_in[1];  // "target" [N,64]
    const int*   nidx = (const int*)d_in[2];    // neg_idx [N]
    float* out = (float*)d_out;

    const int n = in_sizes[2];                  // N rows

    // zero the 4-byte accumulator (async memset is graph-capturable)
    hipMemsetAsync(out, 0, sizeof(float), stream);

    hinge_fused_kernel<<<BLOCKS, TPB, 0, stream>>>(outp, tgt, nidx, out,
                                                   1.0f / (float)n, n);
}

// Round 9
// 36.666 us; speedup vs baseline: 1.1223x; 1.1223x over previous
//
#include <hip/hip_runtime.h>
#include <cmath>

#define MARGIN 0.1f
#define EPS 1e-5f

#define TPB 256
#define BLOCKS 1024
#define RPT 4   // rows per 4-lane group (grid-strided)

typedef float vf4 __attribute__((ext_vector_type(4)));

__device__ __forceinline__ vf4 ntload(const vf4* p) {
    return __builtin_nontemporal_load(p);
}

// Best-known configuration (R5, 36.9 us): persistent 1024-block grid,
// 4 lanes per row, RPT=4 grid-strided rows per group, depth-2 software
// pipeline with static double buffers, all neg-indices preloaded, nt-hint
// on the o-stream only (keeps L2/L3 for the gathered target rows).
// Two-kernel finish: block partials + deterministic single-block reduce
// (single-address atomicAdd across 1024 blocks costs ~18 us in XCD
// cacheline ping-pong — measured R8 — so keep the separate reduce).
__global__ __launch_bounds__(TPB, 4) void hinge_partial_kernel(
    const float* __restrict__ outp,   // [N,64] "output" (v)
    const float* __restrict__ tgt,    // [N,64] "target" (u)
    const int*   __restrict__ nidx,   // [N] negative indices
    float* __restrict__ partials,     // [BLOCKS]
    int n)
{
    const int g   = blockIdx.x * TPB + threadIdx.x;
    const int grp = g >> 2;
    const int sub = g & 3;
    const int G   = (BLOCKS * TPB) >> 2;   // groups in grid

    int  rows[RPT];
    bool valid[RPT];
    #pragma unroll
    for (int p = 0; p < RPT; ++p) {
        const int r = grp + p * G;
        valid[p] = (r < n);
        rows[p]  = valid[p] ? r : 0;
    }

    // preload ALL negative indices up front — no idx->gather chain in the loop
    long j[RPT];
    #pragma unroll
    for (int p = 0; p < RPT; ++p) j[p] = (long)nidx[rows[p]];

    const vf4* ob = reinterpret_cast<const vf4*>(outp);
    const vf4* tb = reinterpret_cast<const vf4*>(tgt);

    float loss = 0.0f;

    vf4 oA[4], tA[4], nA[4];   // buffer A (rows 0, 2)
    vf4 oB[4], tB[4], nB[4];   // buffer B (rows 1, 3)

#define LOADROW(BO, BT, BN, P) do {                                   \
        const vf4* o_ = ob + (size_t)rows[P] * 16 + sub;              \
        const vf4* t_ = tb + (size_t)rows[P] * 16 + sub;              \
        const vf4* n_ = tb + (size_t)j[P]    * 16 + sub;              \
        _Pragma("unroll")                                             \
        for (int k = 0; k < 4; ++k) {                                 \
            BO[k] = ntload(o_ + k * 4);                               \
            BT[k] = t_[k * 4];                                        \
            BN[k] = n_[k * 4];                                        \
        }                                                             \
    } while (0)

#define COMPUTE(BO, BT, BN, P) do {                                   \
        float sp = 0.f, sn = 0.f, un = 0.f, vn = 0.f, wn = 0.f;       \
        _Pragma("unroll")                                             \
        for (int k = 0; k < 4; ++k) {                                 \
            const vf4 ov = BO[k], tv = BT[k], nv = BN[k];             \
            float d;                                                  \
            d = tv.x - ov.x; sp += d * d;                             \
            d = tv.y - ov.y; sp += d * d;                             \
            d = tv.z - ov.z; sp += d * d;                             \
            d = tv.w - ov.w; sp += d * d;                             \
            d = nv.x - ov.x; sn += d * d;                             \
            d = nv.y - ov.y; sn += d * d;                             \
            d = nv.z - ov.z; sn += d * d;                             \
            d = nv.w - ov.w; sn += d * d;                             \
            un += tv.x * tv.x + tv.y * tv.y + tv.z * tv.z + tv.w * tv.w; \
            vn += ov.x * ov.x + ov.y * ov.y + ov.z * ov.z + ov.w * ov.w; \
            wn += nv.x * nv.x + nv.y * nv.y + nv.z * nv.z + nv.w * nv.w; \
        }                                                             \
        _Pragma("unroll")                                             \
        for (int mask = 1; mask <= 2; mask <<= 1) {                   \
            sp += __shfl_xor(sp, mask, 64);                           \
            sn += __shfl_xor(sn, mask, 64);                           \
            un += __shfl_xor(un, mask, 64);                           \
            vn += __shfl_xor(vn, mask, 64);                           \
            wn += __shfl_xor(wn, mask, 64);                           \
        }                                                             \
        if (sub == 0 && valid[P]) {                                   \
            const float xp = 1.0f + 2.0f * sp / ((1.0f - un) * (1.0f - vn)); \
            const float xn = 1.0f + 2.0f * sn / ((1.0f - wn) * (1.0f - vn)); \
            loss += fmaxf(MARGIN + acoshf(fmaxf(xp, 1.0f + EPS))      \
                                 - acoshf(fmaxf(xn, 1.0f + EPS)), 0.0f); \
        }                                                             \
    } while (0)

    LOADROW(oA, tA, nA, 0);
    LOADROW(oB, tB, nB, 1);
    COMPUTE(oA, tA, nA, 0);
    LOADROW(oA, tA, nA, 2);
    COMPUTE(oB, tB, nB, 1);
    LOADROW(oB, tB, nB, 3);
    COMPUTE(oA, tA, nA, 2);
    COMPUTE(oB, tB, nB, 3);

#undef LOADROW
#undef COMPUTE

    // wave(64) shuffle reduce
    #pragma unroll
    for (int off = 32; off > 0; off >>= 1)
        loss += __shfl_down(loss, off, 64);

    __shared__ float ws[4];
    const int lane = threadIdx.x & 63;
    const int wid  = threadIdx.x >> 6;
    if (lane == 0) ws[wid] = loss;
    __syncthreads();
    if (threadIdx.x == 0)
        partials[blockIdx.x] = ws[0] + ws[1] + ws[2] + ws[3];
}

// Stage 2: deterministic single-block reduction of block partials -> mean.
__global__ __launch_bounds__(256) void hinge_final_kernel(
    const float* __restrict__ partials, float* __restrict__ out,
    int nparts, float inv_n)
{
    float s = 0.0f;
    for (int i = threadIdx.x; i < nparts; i += 256)
        s += partials[i];

    #pragma unroll
    for (int off = 32; off > 0; off >>= 1)
        s += __shfl_down(s, off, 64);

    __shared__ float ws[4];
    const int lane = threadIdx.x & 63;
    const int wid  = threadIdx.x >> 6;
    if (lane == 0) ws[wid] = s;
    __syncthreads();
    if (threadIdx.x == 0)
        out[0] = (ws[0] + ws[1] + ws[2] + ws[3]) * inv_n;
}

extern "C" void kernel_launch(void* const* d_in, const int* in_sizes, int n_in,
                              void* d_out, int out_size, void* d_ws, size_t ws_size,
                              hipStream_t stream) {
    const float* outp = (const float*)d_in[0];  // "output" [N,64]
    const float* tgt  = (const float*)d_in[1];  // "target" [N,64]
    const int*   nidx = (const int*)d_in[2];    // neg_idx [N]
    float* out = (float*)d_out;
    float* partials = (float*)d_ws;

    const int n = in_sizes[2];                  // N rows

    hinge_partial_kernel<<<BLOCKS, TPB, 0, stream>>>(outp, tgt, nidx, partials, n);
    hinge_final_kernel<<<1, 256, 0, stream>>>(partials, out, BLOCKS, 1.0f / (float)n);
}